// Round 1
// 261.848 us; speedup vs baseline: 1.0013x; 1.0013x over previous
//
#include <hip/hip_runtime.h>
#include <hip/hip_bf16.h>
#include <math.h>

#define B_   8192
#define F_   48
#define T_   512
#define L_   8
#define NBLK 256
#define THR  512
#define NW   8           // waves per block
#define RPB  32          // rows per block
#define HST  520         // H LDS row stride in shorts (1040B; 65 uint4)
#define ZS   52          // z LDS row stride in floats

typedef unsigned short ushort_t;
typedef unsigned int   uint_t;
typedef __attribute__((ext_vector_type(8))) short short8;
typedef __attribute__((ext_vector_type(4))) float f32x4;

#define MFMA(a,b,c) __builtin_amdgcn_mfma_f32_16x16x32_bf16(a,b,c,0,0,0)

__device__ inline ushort_t f2bf(float x) {
    __hip_bfloat16 h = __float2bfloat16(x);
    return *reinterpret_cast<ushort_t*>(&h);
}
__device__ inline short8 negbf(short8 v) {
    short8 r;
    #pragma unroll
    for (int i = 0; i < 8; ++i) r[i] = v[i] ^ (short)0x8000;
    return r;
}
__device__ inline short8 pack8(float4 a, float4 b) {
    short8 r;
    r[0]=(short)f2bf(a.x); r[1]=(short)f2bf(a.y); r[2]=(short)f2bf(a.z); r[3]=(short)f2bf(a.w);
    r[4]=(short)f2bf(b.x); r[5]=(short)f2bf(b.y); r[6]=(short)f2bf(b.z); r[7]=(short)f2bf(b.w);
    return r;
}

__device__ inline void bar_add(uint_t* cnt) {
    __hip_atomic_fetch_add(cnt, 1u, __ATOMIC_RELEASE, __HIP_MEMORY_SCOPE_AGENT);
}
__device__ inline void bar_wait(uint_t* cnt, uint_t tgt) {
    if (threadIdx.x == 0) {
        while (__hip_atomic_load(cnt, __ATOMIC_RELAXED, __HIP_MEMORY_SCOPE_AGENT) < tgt)
            __builtin_amdgcn_s_sleep(2);
        (void)__hip_atomic_load(cnt, __ATOMIC_ACQUIRE, __HIP_MEMORY_SCOPE_AGENT);
    }
    __syncthreads();
}
__device__ inline float aload(const float* p) {
    return __hip_atomic_load(p, __ATOMIC_RELAXED, __HIP_MEMORY_SCOPE_AGENT);
}
__device__ inline void afadd(float* p, float v) {
    (void)__hip_atomic_fetch_add(p, v, __ATOMIC_RELAXED, __HIP_MEMORY_SCOPE_AGENT);
}

// ---------- prep: frag-linear bf16 layouts + zero barrier counter/slots ----------
// Af: [L][tile32][k2(2)][quad4][m16][8]  (fwd B-frags; wave reads 1KiB contiguous)
// At: [L][ft3][ks16][quad4][m16][8]      (bwd B-frags)
// Df: [ft3][ks16][quad4][m16][8]         (final B-frags)
__global__ __launch_bounds__(256) void k_pre(
    const float* __restrict__ Ar, const float* __restrict__ Ai,
    const float* __restrict__ Dr, const float* __restrict__ Di,
    ushort_t* __restrict__ Afr, ushort_t* __restrict__ Afi,
    ushort_t* __restrict__ Atr, ushort_t* __restrict__ Ati,
    ushort_t* __restrict__ Dfr, ushort_t* __restrict__ Dfi,
    float* __restrict__ slots, uint_t* __restrict__ cnt)
{
    const int gt = blockIdx.x * 256 + threadIdx.x;
    const int gs = gridDim.x * 256;
    if (gt == 0) *cnt = 0u;
    if (gt < 32) slots[gt] = 0.f;
    for (int idx = gt; idx < L_ * 32768; idx += gs) {
        int j = idx & 7, rest = idx >> 3;
        int mm = rest & 15; rest >>= 4;
        int qq = rest & 3;  rest >>= 2;
        int k2 = rest & 1;  rest >>= 1;
        int tile = rest & 31;
        int l = rest >> 5;
        int t = tile * 16 + mm, k = k2 * 32 + qq * 8 + j;
        float vr = 0.f, vi = 0.f;
        if (k < 48) { int g = l * 24576 + t * 48 + k; vr = Ar[g]; vi = Ai[g]; }
        Afr[idx] = f2bf(vr); Afi[idx] = f2bf(vi);
    }
    for (int idx = gt; idx < L_ * 24576; idx += gs) {
        int j = idx & 7, rest = idx >> 3;
        int mm = rest & 15; rest >>= 4;
        int qq = rest & 3;  rest >>= 2;
        int ks = rest & 15; rest >>= 4;
        int ft = rest % 3;
        int l = rest / 3;
        int f = ft * 16 + mm, k = ks * 32 + qq * 8 + j;
        int g = l * 24576 + k * 48 + f;
        Atr[idx] = f2bf(Ar[g]); Ati[idx] = f2bf(Ai[g]);
    }
    for (int idx = gt; idx < 24576; idx += gs) {
        int j = idx & 7, rest = idx >> 3;
        int mm = rest & 15; rest >>= 4;
        int qq = rest & 3;  rest >>= 2;
        int ks = rest & 15;
        int ft = rest >> 4;
        int f = ft * 16 + mm, k = ks * 32 + qq * 8 + j;
        Dfr[idx] = f2bf(Dr[k * 48 + f]); Dfi[idx] = f2bf(Di[k * 48 + f]);
    }
}

// ---------- persistent cooperative kernel ----------
// 256 blocks x 512 threads; block owns rows [blk*32,+32).
// H lives in registers (f32, 64 VGPR/lane); LDS holds z fp32 + Hn bf16 (for bwd GEMM).
// Global reductions: slot-per-layer atomic float adds + release counter barrier.
__global__ __launch_bounds__(THR, 2) void k_lamp(
    const float* __restrict__ u,
    const ushort_t* __restrict__ Afr, const ushort_t* __restrict__ Afi,
    const ushort_t* __restrict__ Atr, const ushort_t* __restrict__ Ati,
    const ushort_t* __restrict__ Dfr, const ushort_t* __restrict__ Dfi,
    const float* __restrict__ th,
    float* slots, uint_t* cnt,
    float* __restrict__ out)
{
    extern __shared__ char dyn[];
    float*    pR   = (float*)dyn;                  // [8][3][16][17] 26112 B
    float*    pI   = pR + 8 * 3 * 16 * 17;         // 26112 B
    float*    zreL = pI + 8 * 3 * 16 * 17;         // 6656 B
    float*    zimL = zreL + RPB * ZS;              // 6656 B
    float*    red8 = zimL + RPB * ZS;              // 64 B
    ushort_t* HreL = (ushort_t*)(red8 + 16);       // 33280 B
    ushort_t* HimL = HreL + RPB * HST;             // 33280 B  => 132160 B

    const int tid = threadIdx.x, blk = blockIdx.x;
    const int row0 = blk * RPB;
    const int wave = tid >> 6, lane = tid & 63;
    const int quad = lane >> 4, m = lane & 15;
    const int rows16 = (wave >> 2) * 16;           // fwd: which 16-row tile
    const int rt = wave >> 2, kq = wave & 3;       // bwd: row-tile / K-quarter
    const float2* u2 = (const float2*)u;
    float* sigS = slots;         // [8]: sigma^2 sums, sigS[l] for layer l
    float* brS  = slots + 8;     // [8]: re count sums
    float* biS  = slots + 16;    // [8]: im count sums
    uint_t tgt = 0;

    // persistent H fragments (f32): H[ct][reg] at (row=rows16+quad*4+reg, col=tile*16+m)
    f32x4 hR[8], hI[8];
    #pragma unroll
    for (int ct = 0; ct < 8; ++ct) { hR[ct] = (f32x4){0,0,0,0}; hI[ct] = (f32x4){0,0,0,0}; }

    // prologue: u -> z LDS, sigma partial -> atomic slot 0
    float acc = 0.f;
    #pragma unroll
    for (int k3 = 0; k3 < 3; ++k3) {
        int j = tid + k3 * THR;
        int r = j / 48, c = j - r * 48;
        float2 v = u2[(row0 + r) * 48 + c];
        zreL[r * ZS + c] = v.x; zimL[r * ZS + c] = v.y;
        acc += v.x * v.x + v.y * v.y;
    }
    #pragma unroll
    for (int s = 32; s > 0; s >>= 1) acc += __shfl_xor(acc, s, 64);
    __syncthreads();                         // also publishes z LDS
    if ((tid & 63) == 0) red8[tid >> 6] = acc;
    __syncthreads();
    if (tid == 0) {
        float t = 0.f;
        #pragma unroll
        for (int w = 0; w < NW; ++w) t += red8[w];
        afadd(&sigS[0], t); bar_add(cnt);
    }
    tgt += NBLK;

    for (int l = 0; l < L_; ++l) {
        // z A-frags from LDS fp32 (K=48 padded to 64)
        const float* zpr = zreL + (rows16 + m) * ZS;
        const float* zpi = zimL + (rows16 + m) * ZS;
        short8 zr0 = pack8(*(const float4*)(zpr + quad * 8), *(const float4*)(zpr + quad * 8 + 4));
        short8 zi0 = pack8(*(const float4*)(zpi + quad * 8), *(const float4*)(zpi + quad * 8 + 4));
        short8 zr1 = {0,0,0,0,0,0,0,0}, zi1 = {0,0,0,0,0,0,0,0};
        if (quad < 2) {
            zr1 = pack8(*(const float4*)(zpr + 32 + quad * 8), *(const float4*)(zpr + 36 + quad * 8));
            zi1 = pack8(*(const float4*)(zpi + 32 + quad * 8), *(const float4*)(zpi + 36 + quad * 8));
        }
        short8 zin0 = negbf(zi0), zin1 = negbf(zi1);

        // forward GEMM accumulating straight onto H_old (R = H + Z in registers)
        const ushort_t* Aflr = Afr + (size_t)l * 32768;
        const ushort_t* Afli = Afi + (size_t)l * 32768;
        #pragma unroll
        for (int ct = 0; ct < 8; ++ct) {
            const int tile = (wave & 3) * 8 + ct;
            const ushort_t* rp = Aflr + (size_t)(tile * 2) * 512 + lane * 8;
            const ushort_t* ip = Afli + (size_t)(tile * 2) * 512 + lane * 8;
            short8 ar0 = *(const short8*)rp;
            short8 ar1 = *(const short8*)(rp + 512);
            short8 ai0 = *(const short8*)ip;
            short8 ai1 = *(const short8*)(ip + 512);
            hR[ct] = MFMA(zr0, ar0, hR[ct]);
            hR[ct] = MFMA(zr1, ar1, hR[ct]);
            hR[ct] = MFMA(zin0, ai0, hR[ct]);
            hR[ct] = MFMA(zin1, ai1, hR[ct]);
            hI[ct] = MFMA(zr0, ai0, hI[ct]);
            hI[ct] = MFMA(zr1, ai1, hI[ct]);
            hI[ct] = MFMA(zi0, ar0, hI[ct]);
            hI[ct] = MFMA(zi1, ar1, hI[ct]);
        }

        // sigma barrier (hidden behind the GEMM above); single broadcast slot read
        bar_wait(cnt, tgt);
        const float lam = th[l * 3] * sqrtf(aload(&sigS[l]) * (1.0f / 48.0f));
        const float th1 = th[l * 3 + 1];

        // activation on registers: Hn = act(R); store Hn bf16 to LDS for bwd GEMM
        float cr = 0.f, ci = 0.f;
        #pragma unroll
        for (int ct = 0; ct < 8; ++ct) {
            const int t = ((wave & 3) * 8 + ct) * 16 + m;
            #pragma unroll
            for (int reg = 0; reg < 4; ++reg) {
                const int lr = rows16 + quad * 4 + reg;
                float Rr = hR[ct][reg], Ri = hI[ct][reg];
                float mr = fabsf(Rr), mi = fabsf(Ri);
                float fr = th1 * copysignf(fmaxf(mr - lam, 0.f), Rr);
                float fi = th1 * copysignf(fmaxf(mi - lam, 0.f), Ri);
                cr += (mr > lam) ? 1.f : 0.f;
                ci += (mi > lam) ? 1.f : 0.f;
                hR[ct][reg] = fr; hI[ct][reg] = fi;
                HreL[lr * HST + t] = f2bf(fr);
                HimL[lr * HST + t] = f2bf(fi);
            }
        }

        if (l == L_ - 1) { __syncthreads(); break; }   // publish Hn for final GEMM

        // combined block reduce of (cr, ci) -> atomic slots; also publishes Hn LDS
        #pragma unroll
        for (int s = 32; s > 0; s >>= 1) { cr += __shfl_xor(cr, s, 64); ci += __shfl_xor(ci, s, 64); }
        __syncthreads();
        if ((tid & 63) == 0) { red8[tid >> 6] = cr; red8[8 + (tid >> 6)] = ci; }
        __syncthreads();
        if (tid == 0) {
            float tr = 0.f, tii = 0.f;
            #pragma unroll
            for (int w = 0; w < NW; ++w) { tr += red8[w]; tii += red8[8 + w]; }
            afadd(&brS[l], tr); afadd(&biS[l], tii); bar_add(cnt);
        }
        tgt += NBLK;

        // backward GEMM: h = Hn @ A; wave (rt,kq) does rows rt*16..+16, K quarter kq
        const ushort_t* Atlr = Atr + (size_t)l * 24576;
        const ushort_t* Atli = Ati + (size_t)l * 24576;
        f32x4 aR[3], aI[3];
        #pragma unroll
        for (int q = 0; q < 3; ++q) { aR[q] = (f32x4){0,0,0,0}; aI[q] = (f32x4){0,0,0,0}; }
        #pragma unroll
        for (int ks = 0; ks < 4; ++ks) {
            const int ksa = kq * 4 + ks;
            const int k0 = ksa * 32 + quad * 8;
            short8 hr = *(const short8*)&HreL[(rt * 16 + m) * HST + k0];
            short8 hi = *(const short8*)&HimL[(rt * 16 + m) * HST + k0];
            short8 hin = negbf(hi);
            #pragma unroll
            for (int ft = 0; ft < 3; ++ft) {
                short8 br = *(const short8*)(Atlr + (size_t)((ft * 16 + ksa) * 64 + lane) * 8);
                short8 bi = *(const short8*)(Atli + (size_t)((ft * 16 + ksa) * 64 + lane) * 8);
                aR[ft] = MFMA(hr, br, aR[ft]);
                aR[ft] = MFMA(hin, bi, aR[ft]);
                aI[ft] = MFMA(hr, bi, aI[ft]);
                aI[ft] = MFMA(hi, br, aI[ft]);
            }
        }
        #pragma unroll
        for (int ft = 0; ft < 3; ++ft) {
            #pragma unroll
            for (int reg = 0; reg < 4; ++reg) {
                pR[((wave * 3 + ft) * 16 + quad * 4 + reg) * 17 + m] = aR[ft][reg];
                pI[((wave * 3 + ft) * 16 + quad * 4 + reg) * 17 + m] = aI[ft][reg];
            }
        }

        // b barrier (hidden behind backward GEMM); its syncthreads publishes pR/pI
        bar_wait(cnt, tgt);
        const float bre = th1 * aload(&brS[l]) * (1.0f / 48.0f);
        const float bim = th1 * aload(&biS[l]) * (1.0f / 48.0f);

        // z update + sigma partial -> atomic slot l+1
        float nrm = 0.f;
        #pragma unroll
        for (int k3 = 0; k3 < 3; ++k3) {
            int j = tid + k3 * THR;
            int r = j / 48, f = j - r * 48;
            int rt2 = r >> 4, lr = r & 15, ft = f >> 4, c = f & 15;
            float hRv = 0.f, hIv = 0.f;
            #pragma unroll
            for (int q = 0; q < 4; ++q) {
                hRv += pR[(((rt2 * 4 + q) * 3 + ft) * 16 + lr) * 17 + c];
                hIv += pI[(((rt2 * 4 + q) * 3 + ft) * 16 + lr) * 17 + c];
            }
            float2 uv = u2[(row0 + r) * 48 + f];
            float zr = zreL[r * ZS + f], zi = zimL[r * ZS + f];
            float znr = uv.x - hRv + bre * zr;
            float zni = uv.y - hIv + bim * zi;
            zreL[r * ZS + f] = znr; zimL[r * ZS + f] = zni;
            nrm += znr * znr + zni * zni;
        }
        #pragma unroll
        for (int s = 32; s > 0; s >>= 1) nrm += __shfl_xor(nrm, s, 64);
        __syncthreads();                 // also protects zreL/pR reads above
        if ((tid & 63) == 0) red8[tid >> 6] = nrm;
        __syncthreads();
        if (tid == 0) {
            float t = 0.f;
            #pragma unroll
            for (int w = 0; w < NW; ++w) t += red8[w];
            afadd(&sigS[l + 1], t); bar_add(cnt);
        }
        tgt += NBLK;
    }

    // final: out = Hn(LDS) @ DFT  (wave (rt,kq), K-split, LDS combine)
    f32x4 fR[3], fI[3];
    #pragma unroll
    for (int q = 0; q < 3; ++q) { fR[q] = (f32x4){0,0,0,0}; fI[q] = (f32x4){0,0,0,0}; }
    #pragma unroll
    for (int ks = 0; ks < 4; ++ks) {
        const int ksa = kq * 4 + ks;
        const int k0 = ksa * 32 + quad * 8;
        short8 hr = *(const short8*)&HreL[(rt * 16 + m) * HST + k0];
        short8 hi = *(const short8*)&HimL[(rt * 16 + m) * HST + k0];
        short8 hin = negbf(hi);
        #pragma unroll
        for (int ft = 0; ft < 3; ++ft) {
            short8 br = *(const short8*)(Dfr + (size_t)((ft * 16 + ksa) * 64 + lane) * 8);
            short8 bi = *(const short8*)(Dfi + (size_t)((ft * 16 + ksa) * 64 + lane) * 8);
            fR[ft] = MFMA(hr, br, fR[ft]);
            fR[ft] = MFMA(hin, bi, fR[ft]);
            fI[ft] = MFMA(hr, bi, fI[ft]);
            fI[ft] = MFMA(hi, br, fI[ft]);
        }
    }
    #pragma unroll
    for (int ft = 0; ft < 3; ++ft) {
        #pragma unroll
        for (int reg = 0; reg < 4; ++reg) {
            pR[((wave * 3 + ft) * 16 + quad * 4 + reg) * 17 + m] = fR[ft][reg];
            pI[((wave * 3 + ft) * 16 + quad * 4 + reg) * 17 + m] = fI[ft][reg];
        }
    }
    __syncthreads();
    float2* out2 = (float2*)out;
    #pragma unroll
    for (int k3 = 0; k3 < 3; ++k3) {
        int j = tid + k3 * THR;
        int r = j / 48, f = j - r * 48;
        int rt2 = r >> 4, lr = r & 15, ft = f >> 4, c = f & 15;
        float hRv = 0.f, hIv = 0.f;
        #pragma unroll
        for (int q = 0; q < 4; ++q) {
            hRv += pR[(((rt2 * 4 + q) * 3 + ft) * 16 + lr) * 17 + c];
            hIv += pI[(((rt2 * 4 + q) * 3 + ft) * 16 + lr) * 17 + c];
        }
        out2[(row0 + r) * 48 + f] = make_float2(hRv, hIv);
    }
}

extern "C" void kernel_launch(void* const* d_in, const int* in_sizes, int n_in,
                              void* d_out, int out_size, void* d_ws, size_t ws_size,
                              hipStream_t stream) {
    (void)in_sizes; (void)n_in; (void)out_size; (void)ws_size;
    const float* u  = (const float*)d_in[0];
    const float* Ar = (const float*)d_in[1];
    const float* Ai = (const float*)d_in[2];
    const float* th = (const float*)d_in[3];
    const float* Dr = (const float*)d_in[4];
    const float* Di = (const float*)d_in[5];
    float* out = (float*)d_out;

    char* p = (char*)d_ws;
    auto alloc = [&](size_t bytes) -> char* {
        char* r = p;
        p += (bytes + 255) & ~(size_t)255;
        return r;
    };
    float*    slots = (float*)alloc(32 * 4);
    uint_t*   cnt   = (uint_t*)alloc(64);
    ushort_t* Afr = (ushort_t*)alloc((size_t)L_ * 32768 * 2);
    ushort_t* Afi = (ushort_t*)alloc((size_t)L_ * 32768 * 2);
    ushort_t* Atr = (ushort_t*)alloc((size_t)L_ * 24576 * 2);
    ushort_t* Ati = (ushort_t*)alloc((size_t)L_ * 24576 * 2);
    ushort_t* Dfr = (ushort_t*)alloc((size_t)24576 * 2);
    ushort_t* Dfi = (ushort_t*)alloc((size_t)24576 * 2);

    k_pre<<<1024, 256, 0, stream>>>(Ar, Ai, Dr, Di, Afr, Afi, Atr, Ati, Dfr, Dfi, slots, cnt);

    const uint_t lds_bytes = 132160;
    hipFuncSetAttribute((const void*)k_lamp,
                        hipFuncAttributeMaxDynamicSharedMemorySize, (int)lds_bytes);
    void* args[] = { (void*)&u, (void*)&Afr, (void*)&Afi, (void*)&Atr, (void*)&Ati,
                     (void*)&Dfr, (void*)&Dfi, (void*)&th,
                     (void*)&slots, (void*)&cnt, (void*)&out };
    hipLaunchCooperativeKernel((void*)k_lamp, dim3(NBLK), dim3(THR), args,
                               lds_bytes, stream);
}